// Round 6
// baseline (231.567 us; speedup 1.0000x reference)
//
#include <hip/hip_runtime.h>
#include <hip/hip_bf16.h>

// Problem: AdvancedAttentionLayer  B=2, S=2048, D=1024, H=16, DH=64
// Round 17: fragment-major K/V LDS layout. r16 counters showed the loop is
// LDS-pipe-bound with STRUCTURAL bank conflicts: in a row-major [64][64]
// bf16 tile every row is 128 B = one full bank sweep, so a wave b128
// fragment read (64 different rows, 8 chunk positions) always puts 8 lanes
// on the same bank-quad -- XOR swizzles can't fix the count (conflict
// counter pinned at 4.19M across r15/r16). Fix: LDS stores K/V tiles in
// MFMA-fragment order (16B slot per (ktile,kstep,lane)), so every in-loop
// read is base + lane*16 = canonical conflict-free stride; the permutation
// moves into the global SOURCE addresses of global_load_lds (linear dest +
// pre-swizzled source + linear read). Split-KV groups, double buffer,
// 1 barrier/iter, setprio, LDS merge all unchanged from r16.

#define B_  2
#define S_  2048
#define D_  1024
#define K_  1024
#define H_  16
#define DH_ 64
#define BS_ (B_*S_)

typedef __hip_bfloat16 bf16;
typedef __attribute__((ext_vector_type(8))) short s8v;    // 8 bf16 = 4 VGPRs
typedef __attribute__((ext_vector_type(4))) short s4v;    // 4 bf16
typedef __attribute__((ext_vector_type(4))) float f4v;    // 16x16 MFMA C/D
typedef __attribute__((ext_vector_type(16))) float f16v;  // 32x32 MFMA C/D

__device__ __forceinline__ float b2f(bf16 x) { return __bfloat162float(x); }
__device__ __forceinline__ bf16  f2b(float x) { return __float2bfloat16(x); }

__device__ __forceinline__ void gl_lds_16B(const bf16* g, bf16* l) {
    __builtin_amdgcn_global_load_lds(
        (const __attribute__((address_space(1))) unsigned int*)g,
        (__attribute__((address_space(3))) unsigned int*)l, 16, 0, 0);
}

// pack two f32 -> two bf16 in one dword (low = a)
__device__ __forceinline__ unsigned cvtpk_bf16(float a, float b) {
    unsigned r;
    asm("v_cvt_pk_bf16_f32 %0, %1, %2" : "=v"(r) : "v"(a), "v"(b));
    return r;
}
// swap hi-half lanes of a with lo-half lanes of b (lane i <-> lane i+32)
__device__ __forceinline__ void plswap(unsigned &a, unsigned &b) {
    asm("v_permlane32_swap_b32 %0, %1" : "+v"(a), "+v"(b));
}

// 0.125 * log2(e): folded QK^T scale so softmax uses raw exp2
#define QSCALE_ 0.1803368801f

// ---------------------------------------------------------------------------
// Fused prep kernel. Grid 5136 blocks x 256:
//   blocks [0,1024):    W transpose, z = blk>>8 (Wq/Wk/Wv/Wo), 64x64 tiles
//   blocks [1024,5120): X fp32 -> bf16, 1024 elems per block
//   blocks [5120,5136): mask int32 -> bf16 0/1
// ---------------------------------------------------------------------------
__global__ __launch_bounds__(256) void prep_kernel(
    const float* __restrict__ X, const int* __restrict__ mask,
    const float* __restrict__ Wq, const float* __restrict__ Wk,
    const float* __restrict__ Wv, const float* __restrict__ Wo,
    bf16* __restrict__ Xb, bf16* __restrict__ mkbf,
    bf16* __restrict__ WTq, bf16* __restrict__ WTk,
    bf16* __restrict__ WTv, bf16* __restrict__ WTo)
{
    __shared__ float Ls[64][68];
    const int blk = blockIdx.x;
    const int t   = threadIdx.x;

    if (blk < 1024) {
        const int z   = blk >> 8;
        const int t16 = blk & 255;
        const int k0  = (t16 >> 4) * 64;
        const int n0  = (t16 & 15) * 64;
        const float* __restrict__ W = (z == 0) ? Wq : (z == 1) ? Wk : (z == 2) ? Wv : Wo;
        bf16* __restrict__ WT       = (z == 0) ? WTq : (z == 1) ? WTk : (z == 2) ? WTv : WTo;

        const int lr = t >> 4;
        const int lc = (t & 15) * 4;
        #pragma unroll
        for (int i = 0; i < 4; i++) {
            const int k = i * 16 + lr;
            const float4 v = *(const float4*)(W + (size_t)(k0 + k) * K_ + n0 + lc);
            Ls[k][lc + 0] = v.x; Ls[k][lc + 1] = v.y;
            Ls[k][lc + 2] = v.z; Ls[k][lc + 3] = v.w;
        }
        __syncthreads();
        #pragma unroll
        for (int i = 0; i < 4; i++) {
            const int n = i * 16 + lr;
            s4v o;
            #pragma unroll
            for (int j = 0; j < 4; j++) {
                bf16 tb = f2b(Ls[lc + j][n]);
                o[j] = *(short*)&tb;
            }
            *(s4v*)(WT + (size_t)(n0 + n) * K_ + k0 + lc) = o;
        }
    } else if (blk < 5120) {
        const size_t idx = ((size_t)(blk - 1024) * 256 + t) * 4;
        const float4 v = *(const float4*)(X + idx);
        bf16 t0 = f2b(v.x), t1 = f2b(v.y), t2 = f2b(v.z), t3 = f2b(v.w);
        s4v o;
        o[0] = *(short*)&t0; o[1] = *(short*)&t1;
        o[2] = *(short*)&t2; o[3] = *(short*)&t3;
        *(s4v*)(Xb + idx) = o;
    } else {
        const int idx = (blk - 5120) * 256 + t;
        mkbf[idx] = f2b(mask[idx] ? 1.0f : 0.0f);
    }
}

// ---------------------------------------------------------------------------
// MFMA GEMM core, 128x128 tile (m97 structure). SWAPPED -> C^T layout.
// ---------------------------------------------------------------------------
template <bool SWAPPED>
__device__ __forceinline__ void gemm_tile(
    const bf16* __restrict__ A, const bf16* __restrict__ BT,
    int m0, int n0, bf16* As, bf16* Bs, f4v acc[4][4])
{
    const int t    = threadIdx.x;
    const int lane = t & 63;
    const int wave = t >> 6;
    const int quad = lane >> 4;
    const int l15  = lane & 15;
    const int wr   = wave >> 1;
    const int wc   = wave & 1;

    const int sr = t >> 3;
    const int sc = (t & 7) * 8;

    for (int kb = 0; kb < K_; kb += 64) {
        #pragma unroll
        for (int i = 0; i < 4; i++) {
            const int r = i * 32 + sr;
            gl_lds_16B(A  + (size_t)(m0 + r) * K_ + kb + sc, As + r * 64 + sc);
            gl_lds_16B(BT + (size_t)(n0 + r) * K_ + kb + sc, Bs + r * 64 + sc);
        }
        __syncthreads();

        #pragma unroll
        for (int ks = 0; ks < 2; ks++) {
            s8v fA[4], fB[4];
            #pragma unroll
            for (int i = 0; i < 4; i++) {
                fA[i] = *(const s8v*)&As[(wr * 64 + i * 16 + l15) * 64 + ks * 32 + quad * 8];
                fB[i] = *(const s8v*)&Bs[(wc * 64 + i * 16 + l15) * 64 + ks * 32 + quad * 8];
            }
            #pragma unroll
            for (int i = 0; i < 4; i++)
                #pragma unroll
                for (int j = 0; j < 4; j++)
                    acc[i][j] = SWAPPED
                        ? __builtin_amdgcn_mfma_f32_16x16x32_bf16(fB[i], fA[j], acc[i][j], 0, 0, 0)
                        : __builtin_amdgcn_mfma_f32_16x16x32_bf16(fA[i], fB[j], acc[i][j], 0, 0, 0);
        }
        __syncthreads();
    }
}

// ---------------------------------------------------------------------------
// QKV projection via MFMA. Grid (32, 8, 3), block 256.
// ---------------------------------------------------------------------------
__global__ __launch_bounds__(256) void proj_qkv_kernel(
    const bf16* __restrict__ Xb,
    const bf16* __restrict__ WTq, const float* __restrict__ bq,
    const bf16* __restrict__ WTk, const float* __restrict__ bk,
    const bf16* __restrict__ WTv, const float* __restrict__ bv,
    const float* __restrict__ emo, const int* __restrict__ mask,
    bf16* __restrict__ q_ws, bf16* __restrict__ k_ws, bf16* __restrict__ v_ws)
{
    const int m0 = blockIdx.x * 128;
    const int n0 = blockIdx.y * 128;
    const int z  = blockIdx.z;

    __shared__ __align__(16) bf16 As[128 * 64];
    __shared__ __align__(16) bf16 Bs[128 * 64];

    const int t    = threadIdx.x;
    const int lane = t & 63;
    const int wave = t >> 6;
    const int quad = lane >> 4;
    const int l15  = lane & 15;
    const int wr   = wave >> 1;
    const int wc   = wave & 1;

    f4v acc[4][4] = {};

    if (z == 0) {
        gemm_tile<false>(Xb, WTq, m0, n0, As, Bs, acc);
        #pragma unroll
        for (int j = 0; j < 4; j++) {
            const int n  = n0 + wc * 64 + j * 16 + l15;
            const int h  = n >> 6, dh = n & 63;
            const float bias_n = bq[n] + emo[n];
            #pragma unroll
            for (int i = 0; i < 4; i++) {
                #pragma unroll
                for (int r = 0; r < 4; r++) {
                    const int m = m0 + wr * 64 + i * 16 + quad * 4 + r;
                    const int b = m >> 11, s = m & 2047;
                    q_ws[(((size_t)(b * H_ + h)) * S_ + s) * DH_ + dh] =
                        f2b((acc[i][j][r] + bias_n) * QSCALE_);
                }
            }
        }
    } else if (z == 1) {
        gemm_tile<false>(Xb, WTk, m0, n0, As, Bs, acc);
        #pragma unroll
        for (int j = 0; j < 4; j++) {
            const int n  = n0 + wc * 64 + j * 16 + l15;
            const int h  = n >> 6, dh = n & 63;
            const float bias_n = bk[n];
            #pragma unroll
            for (int i = 0; i < 4; i++) {
                #pragma unroll
                for (int r = 0; r < 4; r++) {
                    const int m = m0 + wr * 64 + i * 16 + quad * 4 + r;
                    const int b = m >> 11, s = m & 2047;
                    k_ws[(((size_t)(b * H_ + h)) * S_ + s) * DH_ + dh] =
                        f2b(acc[i][j][r] + bias_n);
                }
            }
        }
    } else {
        gemm_tile<true>(Xb, WTv, m0, n0, As, Bs, acc);
        #pragma unroll
        for (int j = 0; j < 4; j++) {
            const int m = m0 + wr * 64 + j * 16 + l15;
            const int b = m >> 11, s = m & 2047;
            const float msk = mask[b * S_ + s] ? 1.0f : 0.0f;
            #pragma unroll
            for (int i = 0; i < 4; i++) {
                #pragma unroll
                for (int r = 0; r < 4; r++) {
                    const int n  = n0 + wc * 64 + i * 16 + quad * 4 + r;
                    const int h  = n >> 6, dh = n & 63;
                    v_ws[(((size_t)(b * H_ + h)) * DH_ + dh) * S_ + s] =
                        f2b((acc[i][j][r] + bv[n]) * msk);
                }
            }
        }
    }
}

// ---------------------------------------------------------------------------
// Output projection: 128x128 tile, grid (32, 8). out = ctx @ Wo + bo (fp32).
// ---------------------------------------------------------------------------
__global__ __launch_bounds__(256) void proj_out_kernel(
    const bf16* __restrict__ ctx, const bf16* __restrict__ WTo,
    const float* __restrict__ bo, float* __restrict__ out)
{
    const int m0 = blockIdx.x * 128;
    const int n0 = blockIdx.y * 128;

    __shared__ __align__(16) bf16 As[128 * 64];
    __shared__ __align__(16) bf16 Bs[128 * 64];

    const int t    = threadIdx.x;
    const int lane = t & 63;
    const int wave = t >> 6;
    const int quad = lane >> 4;
    const int l15  = lane & 15;
    const int wr   = wave >> 1;
    const int wc   = wave & 1;

    f4v acc[4][4] = {};
    gemm_tile<false>(ctx, WTo, m0, n0, As, Bs, acc);

    #pragma unroll
    for (int j = 0; j < 4; j++) {
        const int n = n0 + wc * 64 + j * 16 + l15;
        const float bias_n = bo[n];
        #pragma unroll
        for (int i = 0; i < 4; i++) {
            #pragma unroll
            for (int r = 0; r < 4; r++) {
                const int m = m0 + wr * 64 + i * 16 + quad * 4 + r;
                out[(size_t)m * D_ + n] = acc[i][j][r] + bias_n;
            }
        }
    }
}

// ---------------------------------------------------------------------------
// MFMA flash attention (round-17): 32x32x16 MFMA, split-KV 8-wave blocks,
// FRAGMENT-MAJOR K/V LDS. Grid (B*H=32, S/128=16), 512 threads.
// Wave w: qsub = w&3 (32 q-rows), grp = w>>2 (keys [grp*1024,+1024)).
// LDS tile = 512 x 16B fragment slots, slot c:
//   K: kt=c>>8, kd=(c>>6)&3, fl=c&63 -> K[key=kt*32+(fl&31)][dh=kd*16+(fl>>5)*8]
//   V: dt=c>>8, ks=(c>>6)&3, fl=c&63 -> Vt[dh=dt*32+(fl&31)][key=ks*16+(fl>>5)*8]
// In-loop fragment reads are base + lane*16 -> conflict-free.
//
// MFMA layouts (verified r15/r16):
//   C/D 32x32: col = lane&31, row = (reg&3) + 8*(reg>>2) + 4*(lane>>5)
//   A 32x16:   row = lane&31, k = (lane>>5)*8 + j
//   B 16x32:   col = lane&31, k = (lane>>5)*8 + j
// ---------------------------------------------------------------------------
__global__ __launch_bounds__(512) void attn_kernel(
    const bf16* __restrict__ q_ws, const bf16* __restrict__ k_ws,
    const bf16* __restrict__ v_ws, const bf16* __restrict__ mkbf,
    bf16* __restrict__ ctx)
{
    const int bh = blockIdx.x;
    const int q0 = blockIdx.y * 128;
    const int b  = bh >> 4;
    const int h  = bh & 15;

    // [grp][buf][kv(0=K,1=V)][4096 bf16] -- 65536 B; merge buffer overlays
    __shared__ __align__(16) bf16 lds[2][2][2][4096];

    const int t    = threadIdx.x;
    const int wave = t >> 6;         // 0..7
    const int qsub = wave & 3;       // q subtile (32 rows)
    const int grp  = wave >> 2;      // KV half
    const int tg   = t & 255;        // thread index within group
    const int lane = t & 63;
    const int ql   = lane & 31;      // q col (QK C) / dh col (PV C)
    const int hf   = lane >> 5;

    const int kb_base = grp * 1024;  // this group's key range start

    // ---- Q as B-operand frags: col q = q0+qsub*32+ql, k = kd*16+hf*8 ----
    s8v qf[4];
    #pragma unroll
    for (int kd = 0; kd < 4; kd++)
        qf[kd] = *(const s8v*)(q_ws +
            ((size_t)bh * S_ + q0 + qsub * 32 + ql) * DH_ + kd * 16 + hf * 8);

    f16v oacc[2] = {};   // [dt]: rows=q (reg), cols=dh (ql)
    f16v osum    = {};   // denominator partial, same layout

    const bf16* __restrict__ mbase = mkbf + (size_t)b * S_;
    const bf16* __restrict__ kgbl  = k_ws + (size_t)bh * S_ * DH_;
    const bf16* __restrict__ vgbl  = v_ws + (size_t)bh * DH_ * S_;

    // staging: 2 chunks per thread per tile; chunk c = j*256 + tg
    // (contiguous per wave -> gl_lds dest = wave-uniform base + lane*16)
    int k_key[2], k_dh[2], v_dh[2], v_key[2];
    #pragma unroll
    for (int j = 0; j < 2; j++) {
        const int c  = j * 256 + tg;
        const int fl = c & 63;
        k_key[j] = (c >> 8) * 32 + (fl & 31);          // kt*32 + row
        k_dh[j]  = ((c >> 6) & 3) * 16 + (fl >> 5) * 8; // kd*16 + hf8
        v_dh[j]  = (c >> 8) * 32 + (fl & 31);          // dt*32 + col
        v_key[j] = ((c >> 6) & 3) * 16 + (fl >> 5) * 8; // ks*16 + hf8
    }

    auto stage = [&](int kb_abs, int buf) {
        #pragma unroll
        for (int j = 0; j < 2; j++) {
            const int e = (j * 256 + tg) * 8;          // dest elem (16B slot)
            gl_lds_16B(kgbl + (size_t)(kb_abs + k_key[j]) * DH_ + k_dh[j],
                       &lds[grp][buf][0][e]);
            gl_lds_16B(vgbl + (size_t)v_dh[j] * S_ + kb_abs + v_key[j],
                       &lds[grp][buf][1][e]);
        }
    };

    stage(kb_base, 0);
    __syncthreads();

    int cur = 0;
    for (int kb = 0; kb < 1024; kb += 64) {
        // prefetch next tile into other buffer; drained by end-of-iter barrier
        if (kb + 64 < 1024)
            stage(kb_base + kb + 64, cur ^ 1);

        const bf16* __restrict__ kc = &lds[grp][cur][0][0];
        const bf16* __restrict__ vc = &lds[grp][cur][1][0];

        // ---- S^T = K.Q^T: 2 key-tiles x 4 k-steps of 16 dh ----
        f16v sacc[2] = {};
        __builtin_amdgcn_s_setprio(1);
        #pragma unroll
        for (int kt = 0; kt < 2; kt++) {
            #pragma unroll
            for (int kd = 0; kd < 4; kd++) {
                const s8v kf = *(const s8v*)&kc[((kt * 4 + kd) * 64 + lane) * 8];
                sacc[kt] = __builtin_amdgcn_mfma_f32_32x32x16_bf16(kf, qf[kd], sacc[kt], 0, 0, 0);
            }
        }
        __builtin_amdgcn_s_setprio(0);

        // ---- per 16-key step: exp2 -> pack -> lane-swap -> PV + denom ----
        #pragma unroll
        for (int kt = 0; kt < 2; kt++) {
            #pragma unroll
            for (int hh = 0; hh < 2; hh++) {
                const int ks = kt * 2 + hh;     // 16-key step within 64
                float p[8];
                #pragma unroll
                for (int j = 0; j < 8; j++)
                    p[j] = exp2f(sacc[kt][hh * 8 + j]);
                unsigned w0 = cvtpk_bf16(p[0], p[1]);
                unsigned w1 = cvtpk_bf16(p[2], p[3]);
                unsigned w2 = cvtpk_bf16(p[4], p[5]);
                unsigned w3 = cvtpk_bf16(p[6], p[7]);
                plswap(w0, w2);
                plswap(w1, w3);
                union { unsigned u[4]; s8v v; } af;
                af.u[0] = w0; af.u[1] = w1; af.u[2] = w2; af.u[3] = w3;

                const s8v mf = *(const s8v*)(mbase + kb_base + kb + ks * 16 + hf * 8);
                __builtin_amdgcn_s_setprio(1);
                osum = __builtin_amdgcn_mfma_f32_32x32x16_bf16(af.v, mf, osum, 0, 0, 0);
                #pragma unroll
                for (int dt = 0; dt < 2; dt++) {
                    const s8v vf = *(const s8v*)&vc[((dt * 4 + ks) * 64 + lane) * 8];
                    oacc[dt] = __builtin_amdgcn_mfma_f32_32x32x16_bf16(af.v, vf, oacc[dt], 0, 0, 0);
                }
                __builtin_amdgcn_s_setprio(0);
            }
        }

        // one barrier per iteration: publishes prefetched buffer (vmcnt
        // drain) and protects the just-read buffer from the next staging.
        __syncthreads();
        cur ^= 1;
    }

    // ---- merge the two KV-half partials through LDS (buffers now dead) ---
    // mg layout (floats): oacc at [qsub][qrow 32][dh 64] = 8192,
    //                     osum at 8192 + [qsub][qrow 32]  = 128.
    float* mg = (float*)&lds[0][0][0][0];

    if (grp == 1) {
        #pragma unroll
        for (int r = 0; r < 16; r++) {
            const int qrow = (r & 3) + 8 * (r >> 2) + 4 * hf;
            #pragma unroll
            for (int dt = 0; dt < 2; dt++)
                mg[qsub * 2048 + qrow * 64 + dt * 32 + ql] = oacc[dt][r];
            if (ql == 0)
                mg[8192 + qsub * 32 + qrow] = osum[r];
        }
    }
    __syncthreads();
    if (grp == 0) {
        #pragma unroll
        for (int r = 0; r < 16; r++) {
            const int qrow = (r & 3) + 8 * (r >> 2) + 4 * hf;
            const float den = osum[r] + mg[8192 + qsub * 32 + qrow];
            const float inv = 1.0f / den;
            const int q = q0 + qsub * 32 + qrow;
            #pragma unroll
            for (int dt = 0; dt < 2; dt++) {
                const float o = oacc[dt][r] + mg[qsub * 2048 + qrow * 64 + dt * 32 + ql];
                ctx[((size_t)b * S_ + q) * D_ + h * DH_ + dt * 32 + ql] = f2b(o * inv);
            }
        }
    }
}

// ---------------------------------------------------------------------------
extern "C" void kernel_launch(void* const* d_in, const int* in_sizes, int n_in,
                              void* d_out, int out_size, void* d_ws, size_t ws_size,
                              hipStream_t stream) {
    (void)in_sizes; (void)n_in; (void)out_size; (void)ws_size;

    const float* X    = (const float*)d_in[0];
    const int*   mask = (const int*)d_in[1];
    const float* Wq   = (const float*)d_in[2];
    const float* bq   = (const float*)d_in[3];
    const float* Wk   = (const float*)d_in[4];
    const float* bk   = (const float*)d_in[5];
    const float* Wv   = (const float*)d_in[6];
    const float* bv   = (const float*)d_in[7];
    const float* emo  = (const float*)d_in[8];
    const float* Wo   = (const float*)d_in[9];
    const float* bo   = (const float*)d_in[10];
    float* out = (float*)d_out;

    bf16* q_ws = (bf16*)d_ws;                       // [B,H,S,DH]   8 MB
    bf16* k_ws = q_ws + (size_t)BS_ * D_;           // [B,H,S,DH]   8 MB
    bf16* v_ws = k_ws + (size_t)BS_ * D_;           // [B,H,DH,S]   8 MB
    bf16* ctx  = v_ws + (size_t)BS_ * D_;           // [B,S,D]      8 MB
    bf16* Xb   = ctx  + (size_t)BS_ * D_;           // [BS,D]       8 MB
    bf16* WTq  = Xb   + (size_t)BS_ * D_;           // [N,K]        2 MB
    bf16* WTk  = WTq  + (size_t)D_ * K_;
    bf16* WTv  = WTk  + (size_t)D_ * K_;
    bf16* WTo  = WTv  + (size_t)D_ * K_;
    bf16* mkbf = WTo  + (size_t)D_ * K_;            // [B*S] bf16 mask

    hipLaunchKernelGGL(prep_kernel, dim3(5136), dim3(256), 0, stream,
                       X, mask, Wq, Wk, Wv, Wo, Xb, mkbf, WTq, WTk, WTv, WTo);
    hipLaunchKernelGGL(proj_qkv_kernel, dim3(BS_ / 128, D_ / 128, 3), dim3(256), 0, stream,
                       Xb, WTq, bq, WTk, bk, WTv, bv, emo, mask, q_ws, k_ws, v_ws);
    hipLaunchKernelGGL(attn_kernel, dim3(B_ * H_, S_ / 128), dim3(512), 0, stream,
                       q_ws, k_ws, v_ws, mkbf, ctx);
    hipLaunchKernelGGL(proj_out_kernel, dim3(BS_ / 128, D_ / 128), dim3(256), 0, stream,
                       ctx, WTo, bo, out);
}

// Round 7
// 227.081 us; speedup vs baseline: 1.0198x; 1.0198x over previous
//
#include <hip/hip_runtime.h>
#include <hip/hip_bf16.h>

// Problem: AdvancedAttentionLayer  B=2, S=2048, D=1024, H=16, DH=64
// Round 18: counted-vmcnt pipeline in attn (T3/T4). r13/r16/r17 all cost
// ~5.3k cycles per (128q x 64key) barrier-iteration regardless of MFMA
// shape, occupancy, conflicts, or staging pattern -- the invariant is the
// __syncthreads vmcnt(0) drain per iteration (m233: stage+drain+barrier =
// ~72% of a 2-phase loop). Now: 2 tiles in flight, s_waitcnt vmcnt(4)
// (oldest tile only) + raw s_barrier (no drain) + compute + barrier +
// stage(t+2). vmcnt retires in issue order, so the in-loop mask global
// loads would defeat the counting -> mask moved into LDS (staged once per
// group in prologue). sched_barrier(0) fences per rule #18. Fragment-major
// K/V LDS (0 conflicts), split-KV groups, in-register P, LDS merge all
// unchanged from r17. Prep/proj kernels unchanged.

#define B_  2
#define S_  2048
#define D_  1024
#define K_  1024
#define H_  16
#define DH_ 64
#define BS_ (B_*S_)

typedef __hip_bfloat16 bf16;
typedef __attribute__((ext_vector_type(8))) short s8v;    // 8 bf16 = 4 VGPRs
typedef __attribute__((ext_vector_type(4))) short s4v;    // 4 bf16
typedef __attribute__((ext_vector_type(4))) float f4v;    // 16x16 MFMA C/D
typedef __attribute__((ext_vector_type(16))) float f16v;  // 32x32 MFMA C/D

__device__ __forceinline__ float b2f(bf16 x) { return __bfloat162float(x); }
__device__ __forceinline__ bf16  f2b(float x) { return __float2bfloat16(x); }

__device__ __forceinline__ void gl_lds_16B(const bf16* g, bf16* l) {
    __builtin_amdgcn_global_load_lds(
        (const __attribute__((address_space(1))) unsigned int*)g,
        (__attribute__((address_space(3))) unsigned int*)l, 16, 0, 0);
}

// pack two f32 -> two bf16 in one dword (low = a)
__device__ __forceinline__ unsigned cvtpk_bf16(float a, float b) {
    unsigned r;
    asm("v_cvt_pk_bf16_f32 %0, %1, %2" : "=v"(r) : "v"(a), "v"(b));
    return r;
}
// swap hi-half lanes of a with lo-half lanes of b (lane i <-> lane i+32)
__device__ __forceinline__ void plswap(unsigned &a, unsigned &b) {
    asm("v_permlane32_swap_b32 %0, %1" : "+v"(a), "+v"(b));
}

// 0.125 * log2(e): folded QK^T scale so softmax uses raw exp2
#define QSCALE_ 0.1803368801f

// ---------------------------------------------------------------------------
// Fused prep kernel. Grid 5136 blocks x 256:
//   blocks [0,1024):    W transpose, z = blk>>8 (Wq/Wk/Wv/Wo), 64x64 tiles
//   blocks [1024,5120): X fp32 -> bf16, 1024 elems per block
//   blocks [5120,5136): mask int32 -> bf16 0/1
// ---------------------------------------------------------------------------
__global__ __launch_bounds__(256) void prep_kernel(
    const float* __restrict__ X, const int* __restrict__ mask,
    const float* __restrict__ Wq, const float* __restrict__ Wk,
    const float* __restrict__ Wv, const float* __restrict__ Wo,
    bf16* __restrict__ Xb, bf16* __restrict__ mkbf,
    bf16* __restrict__ WTq, bf16* __restrict__ WTk,
    bf16* __restrict__ WTv, bf16* __restrict__ WTo)
{
    __shared__ float Ls[64][68];
    const int blk = blockIdx.x;
    const int t   = threadIdx.x;

    if (blk < 1024) {
        const int z   = blk >> 8;
        const int t16 = blk & 255;
        const int k0  = (t16 >> 4) * 64;
        const int n0  = (t16 & 15) * 64;
        const float* __restrict__ W = (z == 0) ? Wq : (z == 1) ? Wk : (z == 2) ? Wv : Wo;
        bf16* __restrict__ WT       = (z == 0) ? WTq : (z == 1) ? WTk : (z == 2) ? WTv : WTo;

        const int lr = t >> 4;
        const int lc = (t & 15) * 4;
        #pragma unroll
        for (int i = 0; i < 4; i++) {
            const int k = i * 16 + lr;
            const float4 v = *(const float4*)(W + (size_t)(k0 + k) * K_ + n0 + lc);
            Ls[k][lc + 0] = v.x; Ls[k][lc + 1] = v.y;
            Ls[k][lc + 2] = v.z; Ls[k][lc + 3] = v.w;
        }
        __syncthreads();
        #pragma unroll
        for (int i = 0; i < 4; i++) {
            const int n = i * 16 + lr;
            s4v o;
            #pragma unroll
            for (int j = 0; j < 4; j++) {
                bf16 tb = f2b(Ls[lc + j][n]);
                o[j] = *(short*)&tb;
            }
            *(s4v*)(WT + (size_t)(n0 + n) * K_ + k0 + lc) = o;
        }
    } else if (blk < 5120) {
        const size_t idx = ((size_t)(blk - 1024) * 256 + t) * 4;
        const float4 v = *(const float4*)(X + idx);
        bf16 t0 = f2b(v.x), t1 = f2b(v.y), t2 = f2b(v.z), t3 = f2b(v.w);
        s4v o;
        o[0] = *(short*)&t0; o[1] = *(short*)&t1;
        o[2] = *(short*)&t2; o[3] = *(short*)&t3;
        *(s4v*)(Xb + idx) = o;
    } else {
        const int idx = (blk - 5120) * 256 + t;
        mkbf[idx] = f2b(mask[idx] ? 1.0f : 0.0f);
    }
}

// ---------------------------------------------------------------------------
// MFMA GEMM core, 128x128 tile (m97 structure). SWAPPED -> C^T layout.
// ---------------------------------------------------------------------------
template <bool SWAPPED>
__device__ __forceinline__ void gemm_tile(
    const bf16* __restrict__ A, const bf16* __restrict__ BT,
    int m0, int n0, bf16* As, bf16* Bs, f4v acc[4][4])
{
    const int t    = threadIdx.x;
    const int lane = t & 63;
    const int wave = t >> 6;
    const int quad = lane >> 4;
    const int l15  = lane & 15;
    const int wr   = wave >> 1;
    const int wc   = wave & 1;

    const int sr = t >> 3;
    const int sc = (t & 7) * 8;

    for (int kb = 0; kb < K_; kb += 64) {
        #pragma unroll
        for (int i = 0; i < 4; i++) {
            const int r = i * 32 + sr;
            gl_lds_16B(A  + (size_t)(m0 + r) * K_ + kb + sc, As + r * 64 + sc);
            gl_lds_16B(BT + (size_t)(n0 + r) * K_ + kb + sc, Bs + r * 64 + sc);
        }
        __syncthreads();

        #pragma unroll
        for (int ks = 0; ks < 2; ks++) {
            s8v fA[4], fB[4];
            #pragma unroll
            for (int i = 0; i < 4; i++) {
                fA[i] = *(const s8v*)&As[(wr * 64 + i * 16 + l15) * 64 + ks * 32 + quad * 8];
                fB[i] = *(const s8v*)&Bs[(wc * 64 + i * 16 + l15) * 64 + ks * 32 + quad * 8];
            }
            #pragma unroll
            for (int i = 0; i < 4; i++)
                #pragma unroll
                for (int j = 0; j < 4; j++)
                    acc[i][j] = SWAPPED
                        ? __builtin_amdgcn_mfma_f32_16x16x32_bf16(fB[i], fA[j], acc[i][j], 0, 0, 0)
                        : __builtin_amdgcn_mfma_f32_16x16x32_bf16(fA[i], fB[j], acc[i][j], 0, 0, 0);
        }
        __syncthreads();
    }
}

// ---------------------------------------------------------------------------
// QKV projection via MFMA. Grid (32, 8, 3), block 256.
// ---------------------------------------------------------------------------
__global__ __launch_bounds__(256) void proj_qkv_kernel(
    const bf16* __restrict__ Xb,
    const bf16* __restrict__ WTq, const float* __restrict__ bq,
    const bf16* __restrict__ WTk, const float* __restrict__ bk,
    const bf16* __restrict__ WTv, const float* __restrict__ bv,
    const float* __restrict__ emo, const int* __restrict__ mask,
    bf16* __restrict__ q_ws, bf16* __restrict__ k_ws, bf16* __restrict__ v_ws)
{
    const int m0 = blockIdx.x * 128;
    const int n0 = blockIdx.y * 128;
    const int z  = blockIdx.z;

    __shared__ __align__(16) bf16 As[128 * 64];
    __shared__ __align__(16) bf16 Bs[128 * 64];

    const int t    = threadIdx.x;
    const int lane = t & 63;
    const int wave = t >> 6;
    const int quad = lane >> 4;
    const int l15  = lane & 15;
    const int wr   = wave >> 1;
    const int wc   = wave & 1;

    f4v acc[4][4] = {};

    if (z == 0) {
        gemm_tile<false>(Xb, WTq, m0, n0, As, Bs, acc);
        #pragma unroll
        for (int j = 0; j < 4; j++) {
            const int n  = n0 + wc * 64 + j * 16 + l15;
            const int h  = n >> 6, dh = n & 63;
            const float bias_n = bq[n] + emo[n];
            #pragma unroll
            for (int i = 0; i < 4; i++) {
                #pragma unroll
                for (int r = 0; r < 4; r++) {
                    const int m = m0 + wr * 64 + i * 16 + quad * 4 + r;
                    const int b = m >> 11, s = m & 2047;
                    q_ws[(((size_t)(b * H_ + h)) * S_ + s) * DH_ + dh] =
                        f2b((acc[i][j][r] + bias_n) * QSCALE_);
                }
            }
        }
    } else if (z == 1) {
        gemm_tile<false>(Xb, WTk, m0, n0, As, Bs, acc);
        #pragma unroll
        for (int j = 0; j < 4; j++) {
            const int n  = n0 + wc * 64 + j * 16 + l15;
            const int h  = n >> 6, dh = n & 63;
            const float bias_n = bk[n];
            #pragma unroll
            for (int i = 0; i < 4; i++) {
                #pragma unroll
                for (int r = 0; r < 4; r++) {
                    const int m = m0 + wr * 64 + i * 16 + quad * 4 + r;
                    const int b = m >> 11, s = m & 2047;
                    k_ws[(((size_t)(b * H_ + h)) * S_ + s) * DH_ + dh] =
                        f2b(acc[i][j][r] + bias_n);
                }
            }
        }
    } else {
        gemm_tile<true>(Xb, WTv, m0, n0, As, Bs, acc);
        #pragma unroll
        for (int j = 0; j < 4; j++) {
            const int m = m0 + wr * 64 + j * 16 + l15;
            const int b = m >> 11, s = m & 2047;
            const float msk = mask[b * S_ + s] ? 1.0f : 0.0f;
            #pragma unroll
            for (int i = 0; i < 4; i++) {
                #pragma unroll
                for (int r = 0; r < 4; r++) {
                    const int n  = n0 + wc * 64 + i * 16 + quad * 4 + r;
                    const int h  = n >> 6, dh = n & 63;
                    v_ws[(((size_t)(b * H_ + h)) * DH_ + dh) * S_ + s] =
                        f2b((acc[i][j][r] + bv[n]) * msk);
                }
            }
        }
    }
}

// ---------------------------------------------------------------------------
// Output projection: 128x128 tile, grid (32, 8). out = ctx @ Wo + bo (fp32).
// ---------------------------------------------------------------------------
__global__ __launch_bounds__(256) void proj_out_kernel(
    const bf16* __restrict__ ctx, const bf16* __restrict__ WTo,
    const float* __restrict__ bo, float* __restrict__ out)
{
    const int m0 = blockIdx.x * 128;
    const int n0 = blockIdx.y * 128;

    __shared__ __align__(16) bf16 As[128 * 64];
    __shared__ __align__(16) bf16 Bs[128 * 64];

    const int t    = threadIdx.x;
    const int lane = t & 63;
    const int wave = t >> 6;
    const int quad = lane >> 4;
    const int l15  = lane & 15;
    const int wr   = wave >> 1;
    const int wc   = wave & 1;

    f4v acc[4][4] = {};
    gemm_tile<false>(ctx, WTo, m0, n0, As, Bs, acc);

    #pragma unroll
    for (int j = 0; j < 4; j++) {
        const int n = n0 + wc * 64 + j * 16 + l15;
        const float bias_n = bo[n];
        #pragma unroll
        for (int i = 0; i < 4; i++) {
            #pragma unroll
            for (int r = 0; r < 4; r++) {
                const int m = m0 + wr * 64 + i * 16 + quad * 4 + r;
                out[(size_t)m * D_ + n] = acc[i][j][r] + bias_n;
            }
        }
    }
}

// ---------------------------------------------------------------------------
// MFMA flash attention (round-18): 32x32x16 MFMA, split-KV 8-wave blocks,
// fragment-major K/V LDS, counted-vmcnt pipeline (2 tiles in flight,
// vmcnt(4) per iter -- NEVER drain to 0 in-loop; raw s_barriers).
// Grid (B*H=32, S/128=16), 512 threads.
//
// vmcnt discipline: per-thread VMEM issue order is qf(4) | mask(2 gl_lds)
// | stage t0 (4 gl_lds) | stage t1 (4) | loop { wait vmcnt(4); bar;
// compute (NO VMEM -- mask frags come from LDS); bar; stage t+2 (4) }.
// In-order vmcnt retirement makes vmcnt(4) == "everything up to tile t
// has landed". Last iter waits vmcnt(0).
//
// MFMA layouts (verified r15-r17):
//   C/D 32x32: col = lane&31, row = (reg&3) + 8*(reg>>2) + 4*(lane>>5)
//   A 32x16:   row = lane&31, k = (lane>>5)*8 + j
//   B 16x32:   col = lane&31, k = (lane>>5)*8 + j
// ---------------------------------------------------------------------------
__global__ __launch_bounds__(512) void attn_kernel(
    const bf16* __restrict__ q_ws, const bf16* __restrict__ k_ws,
    const bf16* __restrict__ v_ws, const bf16* __restrict__ mkbf,
    bf16* __restrict__ ctx)
{
    const int bh = blockIdx.x;
    const int q0 = blockIdx.y * 128;
    const int b  = bh >> 4;
    const int h  = bh & 15;

    // [grp][buf][kv(0=K,1=V)][4096 bf16] -- 65536 B; merge buffer overlays
    __shared__ __align__(16) bf16 lds[2][2][2][4096];
    __shared__ __align__(16) bf16 mk_lds[2][1024];   // per-group mask slice

    const int t    = threadIdx.x;
    const int wave = t >> 6;         // 0..7
    const int qsub = wave & 3;       // q subtile (32 rows)
    const int grp  = wave >> 2;      // KV half
    const int tg   = t & 255;        // thread index within group
    const int lane = t & 63;
    const int ql   = lane & 31;      // q col (QK C) / dh col (PV C)
    const int hf   = lane >> 5;

    const int kb_base = grp * 1024;  // this group's key range start

    // ---- Q as B-operand frags: col q = q0+qsub*32+ql, k = kd*16+hf*8 ----
    s8v qf[4];
    #pragma unroll
    for (int kd = 0; kd < 4; kd++)
        qf[kd] = *(const s8v*)(q_ws +
            ((size_t)bh * S_ + q0 + qsub * 32 + ql) * DH_ + kd * 16 + hf * 8);

    f16v oacc[2] = {};   // [dt]: rows=q (reg), cols=dh (ql)
    f16v osum    = {};   // denominator partial, same layout

    const bf16* __restrict__ kgbl  = k_ws + (size_t)bh * S_ * DH_;
    const bf16* __restrict__ vgbl  = v_ws + (size_t)bh * DH_ * S_;

    // staging: 2 chunks per thread per tile; chunk c = j*256 + tg
    // (contiguous per wave -> gl_lds dest = wave-uniform base + lane*16)
    int k_key[2], k_dh[2], v_dh[2], v_key[2];
    #pragma unroll
    for (int j = 0; j < 2; j++) {
        const int c  = j * 256 + tg;
        const int fl = c & 63;
        k_key[j] = (c >> 8) * 32 + (fl & 31);           // kt*32 + row
        k_dh[j]  = ((c >> 6) & 3) * 16 + (fl >> 5) * 8; // kd*16 + hf8
        v_dh[j]  = (c >> 8) * 32 + (fl & 31);           // dt*32 + col
        v_key[j] = ((c >> 6) & 3) * 16 + (fl >> 5) * 8; // ks*16 + hf8
    }

    auto stage = [&](int kb_abs, int buf) {
        #pragma unroll
        for (int j = 0; j < 2; j++) {
            const int e = (j * 256 + tg) * 8;          // dest elem (16B slot)
            gl_lds_16B(kgbl + (size_t)(kb_abs + k_key[j]) * DH_ + k_dh[j],
                       &lds[grp][buf][0][e]);
            gl_lds_16B(vgbl + (size_t)v_dh[j] * S_ + kb_abs + v_key[j],
                       &lds[grp][buf][1][e]);
        }
    };

    // ---- prologue: pin VMEM issue order with sched_barrier fences ----
    __builtin_amdgcn_sched_barrier(0);
    // mask slice (1024 keys, 2KB) -- each wave of the group stages the
    // whole slice redundantly (same data, benign; keeps counts uniform)
    #pragma unroll
    for (int j = 0; j < 2; j++)
        gl_lds_16B(mkbf + (size_t)b * S_ + kb_base + j * 512 + lane * 8,
                   &mk_lds[grp][j * 512 + lane * 8]);
    __builtin_amdgcn_sched_barrier(0);
    stage(kb_base, 0);
    __builtin_amdgcn_sched_barrier(0);
    stage(kb_base + 64, 1);
    __builtin_amdgcn_sched_barrier(0);

    for (int it = 0; it < 16; ++it) {
        const int kb = it * 64;

        // oldest in-flight tile (and mask/qf) landed; NEVER drain in-loop
        if (it < 15) asm volatile("s_waitcnt vmcnt(4)" ::: "memory");
        else         asm volatile("s_waitcnt vmcnt(0)" ::: "memory");
        __builtin_amdgcn_sched_barrier(0);
        __builtin_amdgcn_s_barrier();      // all waves' tile-it loads landed
        __builtin_amdgcn_sched_barrier(0);

        const bf16* __restrict__ kc = &lds[grp][it & 1][0][0];
        const bf16* __restrict__ vc = &lds[grp][it & 1][1][0];

        // ---- S^T = K.Q^T: 2 key-tiles x 4 k-steps of 16 dh ----
        f16v sacc[2] = {};
        __builtin_amdgcn_s_setprio(1);
        #pragma unroll
        for (int kt = 0; kt < 2; kt++) {
            #pragma unroll
            for (int kd = 0; kd < 4; kd++) {
                const s8v kf = *(const s8v*)&kc[((kt * 4 + kd) * 64 + lane) * 8];
                sacc[kt] = __builtin_amdgcn_mfma_f32_32x32x16_bf16(kf, qf[kd], sacc[kt], 0, 0, 0);
            }
        }
        __builtin_amdgcn_s_setprio(0);

        // ---- per 16-key step: exp2 -> pack -> lane-swap -> PV + denom ----
        #pragma unroll
        for (int kt = 0; kt < 2; kt++) {
            #pragma unroll
            for (int hh = 0; hh < 2; hh++) {
                const int ks = kt * 2 + hh;     // 16-key step within 64
                float p[8];
                #pragma unroll
                for (int j = 0; j < 8; j++)
                    p[j] = exp2f(sacc[kt][hh * 8 + j]);
                unsigned w0 = cvtpk_bf16(p[0], p[1]);
                unsigned w1 = cvtpk_bf16(p[2], p[3]);
                unsigned w2 = cvtpk_bf16(p[4], p[5]);
                unsigned w3 = cvtpk_bf16(p[6], p[7]);
                plswap(w0, w2);
                plswap(w1, w3);
                union { unsigned u[4]; s8v v; } af;
                af.u[0] = w0; af.u[1] = w1; af.u[2] = w2; af.u[3] = w3;

                // mask fragment from LDS (same-address broadcast, no VMEM)
                const s8v mf = *(const s8v*)&mk_lds[grp][kb + ks * 16 + hf * 8];
                __builtin_amdgcn_s_setprio(1);
                osum = __builtin_amdgcn_mfma_f32_32x32x16_bf16(af.v, mf, osum, 0, 0, 0);
                #pragma unroll
                for (int dt = 0; dt < 2; dt++) {
                    const s8v vf = *(const s8v*)&vc[((dt * 4 + ks) * 64 + lane) * 8];
                    oacc[dt] = __builtin_amdgcn_mfma_f32_32x32x16_bf16(af.v, vf, oacc[dt], 0, 0, 0);
                }
                __builtin_amdgcn_s_setprio(0);
            }
        }

        // all waves done reading buf[it&1] before it is restaged
        __builtin_amdgcn_sched_barrier(0);
        __builtin_amdgcn_s_barrier();
        __builtin_amdgcn_sched_barrier(0);
        if (it + 2 < 16)
            stage(kb_base + kb + 128, it & 1);
    }

    // ---- merge the two KV-half partials through LDS (buffers now dead) ---
    // mg layout (floats): oacc at [qsub][qrow 32][dh 64] = 8192,
    //                     osum at 8192 + [qsub][qrow 32]  = 128.
    float* mg = (float*)&lds[0][0][0][0];

    if (grp == 1) {
        #pragma unroll
        for (int r = 0; r < 16; r++) {
            const int qrow = (r & 3) + 8 * (r >> 2) + 4 * hf;
            #pragma unroll
            for (int dt = 0; dt < 2; dt++)
                mg[qsub * 2048 + qrow * 64 + dt * 32 + ql] = oacc[dt][r];
            if (ql == 0)
                mg[8192 + qsub * 32 + qrow] = osum[r];
        }
    }
    __syncthreads();
    if (grp == 0) {
        #pragma unroll
        for (int r = 0; r < 16; r++) {
            const int qrow = (r & 3) + 8 * (r >> 2) + 4 * hf;
            const float den = osum[r] + mg[8192 + qsub * 32 + qrow];
            const float inv = 1.0f / den;
            const int q = q0 + qsub * 32 + qrow;
            #pragma unroll
            for (int dt = 0; dt < 2; dt++) {
                const float o = oacc[dt][r] + mg[qsub * 2048 + qrow * 64 + dt * 32 + ql];
                ctx[((size_t)b * S_ + q) * D_ + h * DH_ + dt * 32 + ql] = f2b(o * inv);
            }
        }
    }
}

// ---------------------------------------------------------------------------
extern "C" void kernel_launch(void* const* d_in, const int* in_sizes, int n_in,
                              void* d_out, int out_size, void* d_ws, size_t ws_size,
                              hipStream_t stream) {
    (void)in_sizes; (void)n_in; (void)out_size; (void)ws_size;

    const float* X    = (const float*)d_in[0];
    const int*   mask = (const int*)d_in[1];
    const float* Wq   = (const float*)d_in[2];
    const float* bq   = (const float*)d_in[3];
    const float* Wk   = (const float*)d_in[4];
    const float* bk   = (const float*)d_in[5];
    const float* Wv   = (const float*)d_in[6];
    const float* bv   = (const float*)d_in[7];
    const float* emo  = (const float*)d_in[8];
    const float* Wo   = (const float*)d_in[9];
    const float* bo   = (const float*)d_in[10];
    float* out = (float*)d_out;

    bf16* q_ws = (bf16*)d_ws;                       // [B,H,S,DH]   8 MB
    bf16* k_ws = q_ws + (size_t)BS_ * D_;           // [B,H,S,DH]   8 MB
    bf16* v_ws = k_ws + (size_t)BS_ * D_;           // [B,H,DH,S]   8 MB
    bf16* ctx  = v_ws + (size_t)BS_ * D_;           // [B,S,D]      8 MB
    bf16* Xb   = ctx  + (size_t)BS_ * D_;           // [BS,D]       8 MB
    bf16* WTq  = Xb   + (size_t)BS_ * D_;           // [N,K]        2 MB
    bf16* WTk  = WTq  + (size_t)D_ * K_;
    bf16* WTv  = WTk  + (size_t)D_ * K_;
    bf16* WTo  = WTv  + (size_t)D_ * K_;
    bf16* mkbf = WTo  + (size_t)D_ * K_;            // [B*S] bf16 mask

    hipLaunchKernelGGL(prep_kernel, dim3(5136), dim3(256), 0, stream,
                       X, mask, Wq, Wk, Wv, Wo, Xb, mkbf, WTq, WTk, WTv, WTo);
    hipLaunchKernelGGL(proj_qkv_kernel, dim3(BS_ / 128, D_ / 128, 3), dim3(256), 0, stream,
                       Xb, WTq, bq, WTk, bk, WTv, bv, emo, mask, q_ws, k_ws, v_ws);
    hipLaunchKernelGGL(attn_kernel, dim3(B_ * H_, S_ / 128), dim3(512), 0, stream,
                       q_ws, k_ws, v_ws, mkbf, ctx);
    hipLaunchKernelGGL(proj_out_kernel, dim3(BS_ / 128, D_ / 128), dim3(256), 0, stream,
                       ctx, WTo, bo, out);
}

// Round 8
// 209.436 us; speedup vs baseline: 1.1057x; 1.0842x over previous
//
#include <hip/hip_runtime.h>
#include <hip/hip_bf16.h>

// Problem: AdvancedAttentionLayer  B=2, S=2048, D=1024, H=16, DH=64
// Round 19: single change vs r18 -- exp2f() -> __builtin_amdgcn_exp2f()
// (raw v_exp_f32). r18 counters: MfmaUtil 25% (matches 20 MFMA x 8cyc x
// 4waves/SIMD arithmetic exactly), VALUBusy 50%, conflicts 0, HBM 3.8%.
// The softmax VALU phase dominates; without fast-math, exp2f expands to
// __ocml_exp2_f32 (range-check + fixup, ~5-8 VALU ops each) instead of
// one quarter-rate v_exp_f32. 32 calls/wave-iter make that the largest
// single VALU term. Scores are in-range (O(1) * 0.18) and output feeds
// bf16, so the bare HW exp2 is accuracy-safe. Counted-vmcnt pipeline,
// fragment-major K/V LDS, split-KV groups, in-register P, LDS merge all
// frozen from r18. Prep/proj kernels unchanged.

#define B_  2
#define S_  2048
#define D_  1024
#define K_  1024
#define H_  16
#define DH_ 64
#define BS_ (B_*S_)

typedef __hip_bfloat16 bf16;
typedef __attribute__((ext_vector_type(8))) short s8v;    // 8 bf16 = 4 VGPRs
typedef __attribute__((ext_vector_type(4))) short s4v;    // 4 bf16
typedef __attribute__((ext_vector_type(4))) float f4v;    // 16x16 MFMA C/D
typedef __attribute__((ext_vector_type(16))) float f16v;  // 32x32 MFMA C/D

__device__ __forceinline__ float b2f(bf16 x) { return __bfloat162float(x); }
__device__ __forceinline__ bf16  f2b(float x) { return __float2bfloat16(x); }

__device__ __forceinline__ void gl_lds_16B(const bf16* g, bf16* l) {
    __builtin_amdgcn_global_load_lds(
        (const __attribute__((address_space(1))) unsigned int*)g,
        (__attribute__((address_space(3))) unsigned int*)l, 16, 0, 0);
}

// pack two f32 -> two bf16 in one dword (low = a)
__device__ __forceinline__ unsigned cvtpk_bf16(float a, float b) {
    unsigned r;
    asm("v_cvt_pk_bf16_f32 %0, %1, %2" : "=v"(r) : "v"(a), "v"(b));
    return r;
}
// swap hi-half lanes of a with lo-half lanes of b (lane i <-> lane i+32)
__device__ __forceinline__ void plswap(unsigned &a, unsigned &b) {
    asm("v_permlane32_swap_b32 %0, %1" : "+v"(a), "+v"(b));
}

// raw v_exp_f32 (2^x) -- compiler handles trans-op hazards
__device__ __forceinline__ float hw_exp2(float x) {
    return __builtin_amdgcn_exp2f(x);
}

// 0.125 * log2(e): folded QK^T scale so softmax uses raw exp2
#define QSCALE_ 0.1803368801f

// ---------------------------------------------------------------------------
// Fused prep kernel. Grid 5136 blocks x 256:
//   blocks [0,1024):    W transpose, z = blk>>8 (Wq/Wk/Wv/Wo), 64x64 tiles
//   blocks [1024,5120): X fp32 -> bf16, 1024 elems per block
//   blocks [5120,5136): mask int32 -> bf16 0/1
// ---------------------------------------------------------------------------
__global__ __launch_bounds__(256) void prep_kernel(
    const float* __restrict__ X, const int* __restrict__ mask,
    const float* __restrict__ Wq, const float* __restrict__ Wk,
    const float* __restrict__ Wv, const float* __restrict__ Wo,
    bf16* __restrict__ Xb, bf16* __restrict__ mkbf,
    bf16* __restrict__ WTq, bf16* __restrict__ WTk,
    bf16* __restrict__ WTv, bf16* __restrict__ WTo)
{
    __shared__ float Ls[64][68];
    const int blk = blockIdx.x;
    const int t   = threadIdx.x;

    if (blk < 1024) {
        const int z   = blk >> 8;
        const int t16 = blk & 255;
        const int k0  = (t16 >> 4) * 64;
        const int n0  = (t16 & 15) * 64;
        const float* __restrict__ W = (z == 0) ? Wq : (z == 1) ? Wk : (z == 2) ? Wv : Wo;
        bf16* __restrict__ WT       = (z == 0) ? WTq : (z == 1) ? WTk : (z == 2) ? WTv : WTo;

        const int lr = t >> 4;
        const int lc = (t & 15) * 4;
        #pragma unroll
        for (int i = 0; i < 4; i++) {
            const int k = i * 16 + lr;
            const float4 v = *(const float4*)(W + (size_t)(k0 + k) * K_ + n0 + lc);
            Ls[k][lc + 0] = v.x; Ls[k][lc + 1] = v.y;
            Ls[k][lc + 2] = v.z; Ls[k][lc + 3] = v.w;
        }
        __syncthreads();
        #pragma unroll
        for (int i = 0; i < 4; i++) {
            const int n = i * 16 + lr;
            s4v o;
            #pragma unroll
            for (int j = 0; j < 4; j++) {
                bf16 tb = f2b(Ls[lc + j][n]);
                o[j] = *(short*)&tb;
            }
            *(s4v*)(WT + (size_t)(n0 + n) * K_ + k0 + lc) = o;
        }
    } else if (blk < 5120) {
        const size_t idx = ((size_t)(blk - 1024) * 256 + t) * 4;
        const float4 v = *(const float4*)(X + idx);
        bf16 t0 = f2b(v.x), t1 = f2b(v.y), t2 = f2b(v.z), t3 = f2b(v.w);
        s4v o;
        o[0] = *(short*)&t0; o[1] = *(short*)&t1;
        o[2] = *(short*)&t2; o[3] = *(short*)&t3;
        *(s4v*)(Xb + idx) = o;
    } else {
        const int idx = (blk - 5120) * 256 + t;
        mkbf[idx] = f2b(mask[idx] ? 1.0f : 0.0f);
    }
}

// ---------------------------------------------------------------------------
// MFMA GEMM core, 128x128 tile (m97 structure). SWAPPED -> C^T layout.
// ---------------------------------------------------------------------------
template <bool SWAPPED>
__device__ __forceinline__ void gemm_tile(
    const bf16* __restrict__ A, const bf16* __restrict__ BT,
    int m0, int n0, bf16* As, bf16* Bs, f4v acc[4][4])
{
    const int t    = threadIdx.x;
    const int lane = t & 63;
    const int wave = t >> 6;
    const int quad = lane >> 4;
    const int l15  = lane & 15;
    const int wr   = wave >> 1;
    const int wc   = wave & 1;

    const int sr = t >> 3;
    const int sc = (t & 7) * 8;

    for (int kb = 0; kb < K_; kb += 64) {
        #pragma unroll
        for (int i = 0; i < 4; i++) {
            const int r = i * 32 + sr;
            gl_lds_16B(A  + (size_t)(m0 + r) * K_ + kb + sc, As + r * 64 + sc);
            gl_lds_16B(BT + (size_t)(n0 + r) * K_ + kb + sc, Bs + r * 64 + sc);
        }
        __syncthreads();

        #pragma unroll
        for (int ks = 0; ks < 2; ks++) {
            s8v fA[4], fB[4];
            #pragma unroll
            for (int i = 0; i < 4; i++) {
                fA[i] = *(const s8v*)&As[(wr * 64 + i * 16 + l15) * 64 + ks * 32 + quad * 8];
                fB[i] = *(const s8v*)&Bs[(wc * 64 + i * 16 + l15) * 64 + ks * 32 + quad * 8];
            }
            #pragma unroll
            for (int i = 0; i < 4; i++)
                #pragma unroll
                for (int j = 0; j < 4; j++)
                    acc[i][j] = SWAPPED
                        ? __builtin_amdgcn_mfma_f32_16x16x32_bf16(fB[i], fA[j], acc[i][j], 0, 0, 0)
                        : __builtin_amdgcn_mfma_f32_16x16x32_bf16(fA[i], fB[j], acc[i][j], 0, 0, 0);
        }
        __syncthreads();
    }
}

// ---------------------------------------------------------------------------
// QKV projection via MFMA. Grid (32, 8, 3), block 256.
// ---------------------------------------------------------------------------
__global__ __launch_bounds__(256) void proj_qkv_kernel(
    const bf16* __restrict__ Xb,
    const bf16* __restrict__ WTq, const float* __restrict__ bq,
    const bf16* __restrict__ WTk, const float* __restrict__ bk,
    const bf16* __restrict__ WTv, const float* __restrict__ bv,
    const float* __restrict__ emo, const int* __restrict__ mask,
    bf16* __restrict__ q_ws, bf16* __restrict__ k_ws, bf16* __restrict__ v_ws)
{
    const int m0 = blockIdx.x * 128;
    const int n0 = blockIdx.y * 128;
    const int z  = blockIdx.z;

    __shared__ __align__(16) bf16 As[128 * 64];
    __shared__ __align__(16) bf16 Bs[128 * 64];

    const int t    = threadIdx.x;
    const int lane = t & 63;
    const int wave = t >> 6;
    const int quad = lane >> 4;
    const int l15  = lane & 15;
    const int wr   = wave >> 1;
    const int wc   = wave & 1;

    f4v acc[4][4] = {};

    if (z == 0) {
        gemm_tile<false>(Xb, WTq, m0, n0, As, Bs, acc);
        #pragma unroll
        for (int j = 0; j < 4; j++) {
            const int n  = n0 + wc * 64 + j * 16 + l15;
            const int h  = n >> 6, dh = n & 63;
            const float bias_n = bq[n] + emo[n];
            #pragma unroll
            for (int i = 0; i < 4; i++) {
                #pragma unroll
                for (int r = 0; r < 4; r++) {
                    const int m = m0 + wr * 64 + i * 16 + quad * 4 + r;
                    const int b = m >> 11, s = m & 2047;
                    q_ws[(((size_t)(b * H_ + h)) * S_ + s) * DH_ + dh] =
                        f2b((acc[i][j][r] + bias_n) * QSCALE_);
                }
            }
        }
    } else if (z == 1) {
        gemm_tile<false>(Xb, WTk, m0, n0, As, Bs, acc);
        #pragma unroll
        for (int j = 0; j < 4; j++) {
            const int n  = n0 + wc * 64 + j * 16 + l15;
            const int h  = n >> 6, dh = n & 63;
            const float bias_n = bk[n];
            #pragma unroll
            for (int i = 0; i < 4; i++) {
                #pragma unroll
                for (int r = 0; r < 4; r++) {
                    const int m = m0 + wr * 64 + i * 16 + quad * 4 + r;
                    const int b = m >> 11, s = m & 2047;
                    k_ws[(((size_t)(b * H_ + h)) * S_ + s) * DH_ + dh] =
                        f2b(acc[i][j][r] + bias_n);
                }
            }
        }
    } else {
        gemm_tile<true>(Xb, WTv, m0, n0, As, Bs, acc);
        #pragma unroll
        for (int j = 0; j < 4; j++) {
            const int m = m0 + wr * 64 + j * 16 + l15;
            const int b = m >> 11, s = m & 2047;
            const float msk = mask[b * S_ + s] ? 1.0f : 0.0f;
            #pragma unroll
            for (int i = 0; i < 4; i++) {
                #pragma unroll
                for (int r = 0; r < 4; r++) {
                    const int n  = n0 + wc * 64 + i * 16 + quad * 4 + r;
                    const int h  = n >> 6, dh = n & 63;
                    v_ws[(((size_t)(b * H_ + h)) * DH_ + dh) * S_ + s] =
                        f2b((acc[i][j][r] + bv[n]) * msk);
                }
            }
        }
    }
}

// ---------------------------------------------------------------------------
// Output projection: 128x128 tile, grid (32, 8). out = ctx @ Wo + bo (fp32).
// ---------------------------------------------------------------------------
__global__ __launch_bounds__(256) void proj_out_kernel(
    const bf16* __restrict__ ctx, const bf16* __restrict__ WTo,
    const float* __restrict__ bo, float* __restrict__ out)
{
    const int m0 = blockIdx.x * 128;
    const int n0 = blockIdx.y * 128;

    __shared__ __align__(16) bf16 As[128 * 64];
    __shared__ __align__(16) bf16 Bs[128 * 64];

    const int t    = threadIdx.x;
    const int lane = t & 63;
    const int wave = t >> 6;
    const int quad = lane >> 4;
    const int l15  = lane & 15;
    const int wr   = wave >> 1;
    const int wc   = wave & 1;

    f4v acc[4][4] = {};
    gemm_tile<false>(ctx, WTo, m0, n0, As, Bs, acc);

    #pragma unroll
    for (int j = 0; j < 4; j++) {
        const int n = n0 + wc * 64 + j * 16 + l15;
        const float bias_n = bo[n];
        #pragma unroll
        for (int i = 0; i < 4; i++) {
            #pragma unroll
            for (int r = 0; r < 4; r++) {
                const int m = m0 + wr * 64 + i * 16 + quad * 4 + r;
                out[(size_t)m * D_ + n] = acc[i][j][r] + bias_n;
            }
        }
    }
}

// ---------------------------------------------------------------------------
// MFMA flash attention (round-19): 32x32x16 MFMA, split-KV 8-wave blocks,
// fragment-major K/V LDS, counted-vmcnt pipeline (2 tiles in flight,
// vmcnt(4) per iter -- NEVER drain to 0 in-loop; raw s_barriers), and
// raw v_exp_f32 softmax. Grid (B*H=32, S/128=16), 512 threads.
//
// vmcnt discipline: per-thread VMEM issue order is qf(4) | mask(2 gl_lds)
// | stage t0 (4 gl_lds) | stage t1 (4) | loop { wait vmcnt(4); bar;
// compute (NO VMEM -- mask frags come from LDS); bar; stage t+2 (4) }.
//
// MFMA layouts (verified r15-r18):
//   C/D 32x32: col = lane&31, row = (reg&3) + 8*(reg>>2) + 4*(lane>>5)
//   A 32x16:   row = lane&31, k = (lane>>5)*8 + j
//   B 16x32:   col = lane&31, k = (lane>>5)*8 + j
// ---------------------------------------------------------------------------
__global__ __launch_bounds__(512) void attn_kernel(
    const bf16* __restrict__ q_ws, const bf16* __restrict__ k_ws,
    const bf16* __restrict__ v_ws, const bf16* __restrict__ mkbf,
    bf16* __restrict__ ctx)
{
    const int bh = blockIdx.x;
    const int q0 = blockIdx.y * 128;
    const int b  = bh >> 4;
    const int h  = bh & 15;

    // [grp][buf][kv(0=K,1=V)][4096 bf16] -- 65536 B; merge buffer overlays
    __shared__ __align__(16) bf16 lds[2][2][2][4096];
    __shared__ __align__(16) bf16 mk_lds[2][1024];   // per-group mask slice

    const int t    = threadIdx.x;
    const int wave = t >> 6;         // 0..7
    const int qsub = wave & 3;       // q subtile (32 rows)
    const int grp  = wave >> 2;      // KV half
    const int tg   = t & 255;        // thread index within group
    const int lane = t & 63;
    const int ql   = lane & 31;      // q col (QK C) / dh col (PV C)
    const int hf   = lane >> 5;

    const int kb_base = grp * 1024;  // this group's key range start

    // ---- Q as B-operand frags: col q = q0+qsub*32+ql, k = kd*16+hf*8 ----
    s8v qf[4];
    #pragma unroll
    for (int kd = 0; kd < 4; kd++)
        qf[kd] = *(const s8v*)(q_ws +
            ((size_t)bh * S_ + q0 + qsub * 32 + ql) * DH_ + kd * 16 + hf * 8);

    f16v oacc[2] = {};   // [dt]: rows=q (reg), cols=dh (ql)
    f16v osum    = {};   // denominator partial, same layout

    const bf16* __restrict__ kgbl  = k_ws + (size_t)bh * S_ * DH_;
    const bf16* __restrict__ vgbl  = v_ws + (size_t)bh * DH_ * S_;

    // staging: 2 chunks per thread per tile; chunk c = j*256 + tg
    // (contiguous per wave -> gl_lds dest = wave-uniform base + lane*16)
    int k_key[2], k_dh[2], v_dh[2], v_key[2];
    #pragma unroll
    for (int j = 0; j < 2; j++) {
        const int c  = j * 256 + tg;
        const int fl = c & 63;
        k_key[j] = (c >> 8) * 32 + (fl & 31);           // kt*32 + row
        k_dh[j]  = ((c >> 6) & 3) * 16 + (fl >> 5) * 8; // kd*16 + hf8
        v_dh[j]  = (c >> 8) * 32 + (fl & 31);           // dt*32 + col
        v_key[j] = ((c >> 6) & 3) * 16 + (fl >> 5) * 8; // ks*16 + hf8
    }

    auto stage = [&](int kb_abs, int buf) {
        #pragma unroll
        for (int j = 0; j < 2; j++) {
            const int e = (j * 256 + tg) * 8;          // dest elem (16B slot)
            gl_lds_16B(kgbl + (size_t)(kb_abs + k_key[j]) * DH_ + k_dh[j],
                       &lds[grp][buf][0][e]);
            gl_lds_16B(vgbl + (size_t)v_dh[j] * S_ + kb_abs + v_key[j],
                       &lds[grp][buf][1][e]);
        }
    };

    // ---- prologue: pin VMEM issue order with sched_barrier fences ----
    __builtin_amdgcn_sched_barrier(0);
    // mask slice (1024 keys, 2KB) -- each wave of the group stages the
    // whole slice redundantly (same data, benign; keeps counts uniform)
    #pragma unroll
    for (int j = 0; j < 2; j++)
        gl_lds_16B(mkbf + (size_t)b * S_ + kb_base + j * 512 + lane * 8,
                   &mk_lds[grp][j * 512 + lane * 8]);
    __builtin_amdgcn_sched_barrier(0);
    stage(kb_base, 0);
    __builtin_amdgcn_sched_barrier(0);
    stage(kb_base + 64, 1);
    __builtin_amdgcn_sched_barrier(0);

    for (int it = 0; it < 16; ++it) {
        const int kb = it * 64;

        // oldest in-flight tile (and mask/qf) landed; NEVER drain in-loop
        if (it < 15) asm volatile("s_waitcnt vmcnt(4)" ::: "memory");
        else         asm volatile("s_waitcnt vmcnt(0)" ::: "memory");
        __builtin_amdgcn_sched_barrier(0);
        __builtin_amdgcn_s_barrier();      // all waves' tile-it loads landed
        __builtin_amdgcn_sched_barrier(0);

        const bf16* __restrict__ kc = &lds[grp][it & 1][0][0];
        const bf16* __restrict__ vc = &lds[grp][it & 1][1][0];

        // ---- S^T = K.Q^T: 2 key-tiles x 4 k-steps of 16 dh ----
        f16v sacc[2] = {};
        __builtin_amdgcn_s_setprio(1);
        #pragma unroll
        for (int kt = 0; kt < 2; kt++) {
            #pragma unroll
            for (int kd = 0; kd < 4; kd++) {
                const s8v kf = *(const s8v*)&kc[((kt * 4 + kd) * 64 + lane) * 8];
                sacc[kt] = __builtin_amdgcn_mfma_f32_32x32x16_bf16(kf, qf[kd], sacc[kt], 0, 0, 0);
            }
        }
        __builtin_amdgcn_s_setprio(0);

        // ---- per 16-key step: exp2 -> pack -> lane-swap -> PV + denom ----
        #pragma unroll
        for (int kt = 0; kt < 2; kt++) {
            #pragma unroll
            for (int hh = 0; hh < 2; hh++) {
                const int ks = kt * 2 + hh;     // 16-key step within 64
                float p[8];
                #pragma unroll
                for (int j = 0; j < 8; j++)
                    p[j] = hw_exp2(sacc[kt][hh * 8 + j]);
                unsigned w0 = cvtpk_bf16(p[0], p[1]);
                unsigned w1 = cvtpk_bf16(p[2], p[3]);
                unsigned w2 = cvtpk_bf16(p[4], p[5]);
                unsigned w3 = cvtpk_bf16(p[6], p[7]);
                plswap(w0, w2);
                plswap(w1, w3);
                union { unsigned u[4]; s8v v; } af;
                af.u[0] = w0; af.u[1] = w1; af.u[2] = w2; af.u[3] = w3;

                // mask fragment from LDS (same-address broadcast, no VMEM)
                const s8v mf = *(const s8v*)&mk_lds[grp][kb + ks * 16 + hf * 8];
                __builtin_amdgcn_s_setprio(1);
                osum = __builtin_amdgcn_mfma_f32_32x32x16_bf16(af.v, mf, osum, 0, 0, 0);
                #pragma unroll
                for (int dt = 0; dt < 2; dt++) {
                    const s8v vf = *(const s8v*)&vc[((dt * 4 + ks) * 64 + lane) * 8];
                    oacc[dt] = __builtin_amdgcn_mfma_f32_32x32x16_bf16(af.v, vf, oacc[dt], 0, 0, 0);
                }
                __builtin_amdgcn_s_setprio(0);
            }
        }

        // all waves done reading buf[it&1] before it is restaged
        __builtin_amdgcn_sched_barrier(0);
        __builtin_amdgcn_s_barrier();
        __builtin_amdgcn_sched_barrier(0);
        if (it + 2 < 16)
            stage(kb_base + kb + 128, it & 1);
    }

    // ---- merge the two KV-half partials through LDS (buffers now dead) ---
    // mg layout (floats): oacc at [qsub][qrow 32][dh 64] = 8192,
    //                     osum at 8192 + [qsub][qrow 32]  = 128.
    float* mg = (float*)&lds[0][0][0][0];

    if (grp == 1) {
        #pragma unroll
        for (int r = 0; r < 16; r++) {
            const int qrow = (r & 3) + 8 * (r >> 2) + 4 * hf;
            #pragma unroll
            for (int dt = 0; dt < 2; dt++)
                mg[qsub * 2048 + qrow * 64 + dt * 32 + ql] = oacc[dt][r];
            if (ql == 0)
                mg[8192 + qsub * 32 + qrow] = osum[r];
        }
    }
    __syncthreads();
    if (grp == 0) {
        #pragma unroll
        for (int r = 0; r < 16; r++) {
            const int qrow = (r & 3) + 8 * (r >> 2) + 4 * hf;
            const float den = osum[r] + mg[8192 + qsub * 32 + qrow];
            const float inv = 1.0f / den;
            const int q = q0 + qsub * 32 + qrow;
            #pragma unroll
            for (int dt = 0; dt < 2; dt++) {
                const float o = oacc[dt][r] + mg[qsub * 2048 + qrow * 64 + dt * 32 + ql];
                ctx[((size_t)b * S_ + q) * D_ + h * DH_ + dt * 32 + ql] = f2b(o * inv);
            }
        }
    }
}

// ---------------------------------------------------------------------------
extern "C" void kernel_launch(void* const* d_in, const int* in_sizes, int n_in,
                              void* d_out, int out_size, void* d_ws, size_t ws_size,
                              hipStream_t stream) {
    (void)in_sizes; (void)n_in; (void)out_size; (void)ws_size;

    const float* X    = (const float*)d_in[0];
    const int*   mask = (const int*)d_in[1];
    const float* Wq   = (const float*)d_in[2];
    const float* bq   = (const float*)d_in[3];
    const float* Wk   = (const float*)d_in[4];
    const float* bk   = (const float*)d_in[5];
    const float* Wv   = (const float*)d_in[6];
    const float* bv   = (const float*)d_in[7];
    const float* emo  = (const float*)d_in[8];
    const float* Wo   = (const float*)d_in[9];
    const float* bo   = (const float*)d_in[10];
    float* out = (float*)d_out;

    bf16* q_ws = (bf16*)d_ws;                       // [B,H,S,DH]   8 MB
    bf16* k_ws = q_ws + (size_t)BS_ * D_;           // [B,H,S,DH]   8 MB
    bf16* v_ws = k_ws + (size_t)BS_ * D_;           // [B,H,DH,S]   8 MB
    bf16* ctx  = v_ws + (size_t)BS_ * D_;           // [B,S,D]      8 MB
    bf16* Xb   = ctx  + (size_t)BS_ * D_;           // [BS,D]       8 MB
    bf16* WTq  = Xb   + (size_t)BS_ * D_;           // [N,K]        2 MB
    bf16* WTk  = WTq  + (size_t)D_ * K_;
    bf16* WTv  = WTk  + (size_t)D_ * K_;
    bf16* WTo  = WTv  + (size_t)D_ * K_;
    bf16* mkbf = WTo  + (size_t)D_ * K_;            // [B*S] bf16 mask

    hipLaunchKernelGGL(prep_kernel, dim3(5136), dim3(256), 0, stream,
                       X, mask, Wq, Wk, Wv, Wo, Xb, mkbf, WTq, WTk, WTv, WTo);
    hipLaunchKernelGGL(proj_qkv_kernel, dim3(BS_ / 128, D_ / 128, 3), dim3(256), 0, stream,
                       Xb, WTq, bq, WTk, bk, WTv, bv, emo, mask, q_ws, k_ws, v_ws);
    hipLaunchKernelGGL(attn_kernel, dim3(B_ * H_, S_ / 128), dim3(512), 0, stream,
                       q_ws, k_ws, v_ws, mkbf, ctx);
    hipLaunchKernelGGL(proj_out_kernel, dim3(BS_ / 128, D_ / 128), dim3(256), 0, stream,
                       ctx, WTo, bo, out);
}